// Round 7
// baseline (680.653 us; speedup 1.0000x reference)
//
#include <hip/hip_runtime.h>
#include <hip/hip_bf16.h>

// deformable_cross_grd_attention — MI355X/gfx950
// B=4, NQ=16384, EMBED=256, HEADS=8, HEAD_DIM=32, LEVELS=4, POINTS=4, NV=5440
//
// Pipeline: grd transpose/pad (bf16) -> 4 proj GEMMs (level-major VAL) -> GN ->
// value GEMM -> off/attw GEMMs -> softmax -> 2-phase bilinear sampler ->
// out GEMM (+2Q residual) -> FFN in two M-halves.
//
// r6 changes: (1) sampler LDS entries XOR-swizzled (tap^h) to kill the 8-way
// bank conflict (2.5e7/dispatch); (2) gemm_bt bf16-X path stages As/Bs via
// global_load_lds width=16 (no VGPR round-trip).
//
// VAL/VALB/V rows are LEVEL-MAJOR: row = startB[l] + b*HW_l + hw,
// startB = {0, 16384, 20480, 21504} (rows), 21760 rows total.
//
// Workspace overlay timeline (PEAK = 90,374,144 B, proven r4-r6):
//   [0, 983040)          WT_* bf16 weights — live whole launch
//   [983040, 1769472)    WTP0..3 — dead after proj GEMMs
//   [1769472, 5308416)   XP0..3 — dead after proj GEMMs
//   [34406400, 56688640) VAL f32 — dead after GN
//   [23265280, 34406400) VALB bf16 — dead after value GEMM
//   [983040, 23265280)   V f32 — dead after sampler
//   [23265280, 56819712) AW f32 — overlays dead VALB+VAL
//   [56819712, 90374144) ATT bf16 — sampler -> out GEMM
//   [983040, 34537472)   FUSEDB bf16 — overlays dead V/AW-head
//   [34537472, 68091904) HIDH bf16 — per FFN half
//   [68091904, 84869120) T16H bf16 — per FFN half
//   OFFS f32 (64MB) = d_out; dead before out-GEMM writes FUSED there.

#define NQc 16384
#define NVc 5440

typedef __attribute__((ext_vector_type(8))) short short8;
typedef __attribute__((ext_vector_type(4))) short short4v;
typedef __attribute__((ext_vector_type(4))) float f32x4;

// global_load_lds: 16B per lane, LDS dest = wave-uniform base + lane*16.
#define GLOAD16(gp, lp)                                                        \
  __builtin_amdgcn_global_load_lds(                                           \
      (const __attribute__((address_space(1))) unsigned int*)(gp),            \
      (__attribute__((address_space(3))) unsigned int*)(lp), 16, 0, 0)

__device__ __forceinline__ float wred(float v) {
#pragma unroll
  for (int o = 32; o > 0; o >>= 1) v += __shfl_down(v, o);
  return v;
}

// ---------------- weight transpose + cast:  W[K][N] fp32 -> Wt[N][K] bf16 ----
__global__ __launch_bounds__(256) void tcast_kernel(
    const float* __restrict__ w, __hip_bfloat16* __restrict__ wt, int K, int N) {
  int i = blockIdx.x * 256 + threadIdx.x;
  if (i < K * N) {
    int k = i / N, n = i - k * N;
    wt[(size_t)n * K + k] = __float2bfloat16(w[i]);
  }
}

// ------ weight transpose + cast + K-pad: W[K][N] fp32 -> Wt[N][Kp] bf16 ------
__global__ __launch_bounds__(256) void tcast_pad_kernel(
    const float* __restrict__ w, __hip_bfloat16* __restrict__ wt,
    int K, int Kp, int N) {
  int i = blockIdx.x * 256 + threadIdx.x;
  if (i < N * Kp) {
    int n = i / Kp, k = i - n * Kp;
    wt[i] = (k < K) ? __float2bfloat16(w[k * N + n]) : __float2bfloat16(0.f);
  }
}

// ------ grd transpose + cast + K-pad: element-parallel ----------------------
__global__ __launch_bounds__(256) void tpad_kernel(
    const float* __restrict__ grd, __hip_bfloat16* __restrict__ xp,
    int C, int Kp, int HW, int total) {
  const int i = blockIdx.x * 256 + threadIdx.x;   // row*Kp + k
  if (i >= total) return;
  const int row = i / Kp;                          // b*HW + hw
  const int k = i - row * Kp;
  const int b = row / HW;
  const int hw = row - b * HW;
  xp[i] = (k < C) ? __float2bfloat16(grd[((size_t)b * C + k) * HW + hw])
                  : __float2bfloat16(0.f);
}

// ---------------- GroupNorm (32 groups of 8 ch) -> bf16, level-major --------
__global__ __launch_bounds__(256) void gn_kernel(
    const float* __restrict__ val, __hip_bfloat16* __restrict__ valb,
    const float* __restrict__ gg0, const float* __restrict__ gb0,
    const float* __restrict__ gg1, const float* __restrict__ gb1,
    const float* __restrict__ gg2, const float* __restrict__ gb2,
    const float* __restrict__ gg3, const float* __restrict__ gb3) {
  const int bid = blockIdx.x;            // b*128 + l*32 + grp
  const int grp = bid & 31;
  const int l = (bid >> 5) & 3;
  const int b = bid >> 7;
  int HW, startB; const float *gg, *gbeta;
  if (l == 0)      { HW = 4096; startB = 0;     gg = gg0; gbeta = gb0; }
  else if (l == 1) { HW = 1024; startB = 16384; gg = gg1; gbeta = gb1; }
  else if (l == 2) { HW = 256;  startB = 20480; gg = gg2; gbeta = gb2; }
  else             { HW = 64;   startB = 21504; gg = gg3; gbeta = gb3; }
  const int n = HW * 8;
  const size_t base = ((size_t)(startB + b * HW)) * 256 + grp * 8;
  float s = 0.f, s2 = 0.f;
  for (int i = threadIdx.x; i < n; i += 256) {
    float x = val[base + (size_t)(i >> 3) * 256 + (i & 7)];
    s += x; s2 += x * x;
  }
  s = wred(s); s2 = wred(s2);
  __shared__ float red[8];
  const int wv = threadIdx.x >> 6;
  if ((threadIdx.x & 63) == 0) { red[wv] = s; red[4 + wv] = s2; }
  __syncthreads();
  const float S = red[0] + red[1] + red[2] + red[3];
  const float S2 = red[4] + red[5] + red[6] + red[7];
  const float inv_n = 1.f / (float)n;
  const float mu = S * inv_n;
  const float var = S2 * inv_n - mu * mu;
  const float rstd = rsqrtf(var + 1e-5f);
  for (int i = threadIdx.x; i < n; i += 256) {
    const int j = i & 7;
    const int e = grp * 8 + j;
    const size_t idx = base + (size_t)(i >> 3) * 256 + j;
    const float y = (val[idx] - mu) * rstd * gg[e] + gbeta[e];
    valb[idx] = __float2bfloat16(y);
  }
}

// ---------------- bf16 MFMA GEMM: C[M][N] = X[M][K] * Wt[N][K]^T + bias ------
// 128x128 tile, BK=64, 4 waves (2x2), 4x4 16x16x32 frags per wave.
// !XF32: As/Bs staged via global_load_lds (16B/lane, linear LDS).
// XF32: X fp32, converted to bf16 during reg staging.
// MODE 0: Cf=f32(acc+bias)  1: Cb=bf16(relu)  2: +2Q dual-write  3: Cb=bf16
template <int MODE, bool XF32>
__global__ __launch_bounds__(256) void gemm_bt(
    const void* __restrict__ Xv, const __hip_bfloat16* __restrict__ Wt,
    const float* __restrict__ bias, float* __restrict__ Cf,
    __hip_bfloat16* __restrict__ Cb, const float* __restrict__ Qres,
    int M, int N, int K) {
  const int m0 = blockIdx.x * 128;
  const int n0 = blockIdx.y * 128;
  const int tid = threadIdx.x;
  const int wave = tid >> 6;
  const int lane = tid & 63;
  const int wm = wave >> 1;
  const int wn = wave & 1;
  const int l15 = lane & 15;
  const int l4 = lane >> 4;
  __shared__ __align__(16) __hip_bfloat16 As[128 * 64];
  __shared__ __align__(16) __hip_bfloat16 Bs[128 * 64];
  f32x4 acc[4][4];
#pragma unroll
  for (int m = 0; m < 4; ++m)
#pragma unroll
    for (int n = 0; n < 4; ++n) acc[m][n] = (f32x4){0.f, 0.f, 0.f, 0.f};

  for (int k0 = 0; k0 < K; k0 += 64) {
#pragma unroll
    for (int j = 0; j < 4; ++j) {
      const int e = (j * 256 + tid) * 8;
      const int r = e >> 6;
      const int k = e & 63;
      if constexpr (XF32) {
        const float* Xf = (const float*)Xv;
        const float4 a = *reinterpret_cast<const float4*>(&Xf[(size_t)(m0 + r) * K + k0 + k]);
        const float4 b = *reinterpret_cast<const float4*>(&Xf[(size_t)(m0 + r) * K + k0 + k + 4]);
        union { __hip_bfloat16 h[8]; short8 v; } u;
        u.h[0] = __float2bfloat16(a.x); u.h[1] = __float2bfloat16(a.y);
        u.h[2] = __float2bfloat16(a.z); u.h[3] = __float2bfloat16(a.w);
        u.h[4] = __float2bfloat16(b.x); u.h[5] = __float2bfloat16(b.y);
        u.h[6] = __float2bfloat16(b.z); u.h[7] = __float2bfloat16(b.w);
        *reinterpret_cast<short8*>(&As[e]) = u.v;
        *reinterpret_cast<short8*>(&Bs[e]) =
            *reinterpret_cast<const short8*>(&Wt[(size_t)(n0 + r) * K + k0 + k]);
      } else {
        const __hip_bfloat16* Xb = (const __hip_bfloat16*)Xv;
        GLOAD16(&Xb[(size_t)(m0 + r) * K + k0 + k], &As[e]);
        GLOAD16(&Wt[(size_t)(n0 + r) * K + k0 + k], &Bs[e]);
      }
    }
    __syncthreads();
#pragma unroll
    for (int ks = 0; ks < 2; ++ks) {
      short8 a[4], bfr[4];
#pragma unroll
      for (int m = 0; m < 4; ++m)
        a[m] = *reinterpret_cast<const short8*>(
            &As[(wm * 64 + m * 16 + l15) * 64 + ks * 32 + l4 * 8]);
#pragma unroll
      for (int n = 0; n < 4; ++n)
        bfr[n] = *reinterpret_cast<const short8*>(
            &Bs[(wn * 64 + n * 16 + l15) * 64 + ks * 32 + l4 * 8]);
#pragma unroll
      for (int m = 0; m < 4; ++m)
#pragma unroll
        for (int n = 0; n < 4; ++n)
          acc[m][n] = __builtin_amdgcn_mfma_f32_16x16x32_bf16(a[m], bfr[n], acc[m][n], 0, 0, 0);
    }
    __syncthreads();
  }

#pragma unroll
  for (int m = 0; m < 4; ++m) {
    const int row0 = m0 + wm * 64 + m * 16 + l4 * 4;
#pragma unroll
    for (int n = 0; n < 4; ++n) {
      const int col = n0 + wn * 64 + n * 16 + l15;
      const float bv = bias[col];
#pragma unroll
      for (int r = 0; r < 4; ++r) {
        const size_t ci = (size_t)(row0 + r) * N + col;
        float f = acc[m][n][r] + bv;
        if (MODE == 0) {
          Cf[ci] = f;
        } else if (MODE == 1) {
          Cb[ci] = __float2bfloat16(fmaxf(f, 0.f));
        } else if (MODE == 2) {
          f += 2.f * Qres[ci];
          Cf[ci] = f;
          Cb[ci] = __float2bfloat16(f);
        } else {
          Cb[ci] = __float2bfloat16(f);
        }
      }
    }
  }
}

// ---------------- softmax over 16 (one (b,q,h) row per thread) --------------
__global__ __launch_bounds__(256) void softmax_kernel(float* __restrict__ aw) {
  const size_t t = (size_t)blockIdx.x * 256 + threadIdx.x;
  float* p = aw + t * 16;
  float v[16];
  *reinterpret_cast<float4*>(&v[0])  = *reinterpret_cast<const float4*>(p + 0);
  *reinterpret_cast<float4*>(&v[4])  = *reinterpret_cast<const float4*>(p + 4);
  *reinterpret_cast<float4*>(&v[8])  = *reinterpret_cast<const float4*>(p + 8);
  *reinterpret_cast<float4*>(&v[12]) = *reinterpret_cast<const float4*>(p + 12);
  float mx = v[0];
#pragma unroll
  for (int j = 1; j < 16; ++j) mx = fmaxf(mx, v[j]);
  float sum = 0.f;
#pragma unroll
  for (int j = 0; j < 16; ++j) { v[j] = __expf(v[j] - mx); sum += v[j]; }
  const float inv = 1.f / sum;
#pragma unroll
  for (int j = 0; j < 16; ++j) v[j] *= inv;
  *reinterpret_cast<float4*>(p + 0)  = *reinterpret_cast<const float4*>(&v[0]);
  *reinterpret_cast<float4*>(p + 4)  = *reinterpret_cast<const float4*>(&v[4]);
  *reinterpret_cast<float4*>(p + 8)  = *reinterpret_cast<const float4*>(&v[8]);
  *reinterpret_cast<float4*>(p + 12) = *reinterpret_cast<const float4*>(&v[12]);
}

// ---------------- deformable bilinear sampler (2-phase, swizzled LDS) -------
// block = 4 queries; 256 threads. V is level-major: row = startB[l]+b*HW_l+pos.
// LDS entry for (q,h,tap) stored at physical tap' = tap ^ (h&7): at fixed tap,
// the 8 h-groups then hit 8 distinct bank quads (4*((tap^h)&7)) -> no conflict.
__global__ __launch_bounds__(256) void sampler_kernel(
    const float* __restrict__ V, const float* __restrict__ OFFS,
    const float* __restrict__ AW, __hip_bfloat16* __restrict__ ATT) {
  __shared__ int   sIdx[512 * 4];
  __shared__ float sW[512 * 4];
  const int blk = blockIdx.x;              // [0, B*NQ/4)
  const int b = blk >> 12;                 // NQ/4 = 4096 blocks per batch
  const int q0 = (blk & 4095) << 2;        // within-batch first query
  const int bid0 = blk << 2;               // global row (b*NQ + q0)

  // ---- phase 1: geometry ----
  for (int j = threadIdx.x; j < 512; j += 256) {
    const int q   = j >> 7;                // 0..3
    const int h   = (j >> 4) & 7;
    const int tap = j & 15;                // l*4 + p
    const int l = tap >> 2;
    const int gq = bid0 + q;
    const int qq = q0 + q;
    const float rx = (float)(qq & 127) * (1.f / 127.f);
    const float ry = (float)(qq >> 7) * (1.f / 127.f);
    const float2 oxy = *reinterpret_cast<const float2*>(
        &OFFS[(size_t)gq * 256 + h * 32 + tap * 2]);
    const float aw = AW[(size_t)gq * 128 + h * 16 + tap];
    const int W = 64 >> l;
    const int HWl = W * W;
    const int startB = (l == 0) ? 0 : (l == 1) ? 16384 : (l == 2) ? 20480 : 21504;
    const int rowbase = startB + b * HWl;
    const float fW = (float)W;
    const float x = rx * fW + oxy.x - 0.5f;
    const float y = ry * fW + oxy.y - 0.5f;
    const float x0f = floorf(x);
    const float y0f = floorf(y);
    const int x0 = (int)x0f;
    const int y0 = (int)y0f;
    const float dx = x - x0f;
    const float dy = y - y0f;
    const int x1 = x0 + 1, y1 = y0 + 1;
    const float mx0 = (x0 >= 0 && x0 < W) ? 1.f : 0.f;
    const float mx1 = (x1 >= 0 && x1 < W) ? 1.f : 0.f;
    const float my0 = (y0 >= 0 && y0 < W) ? 1.f : 0.f;
    const float my1 = (y1 >= 0 && y1 < W) ? 1.f : 0.f;
    const int x0c = min(max(x0, 0), W - 1);
    const int x1c = min(max(x1, 0), W - 1);
    const int y0c = min(max(y0, 0), W - 1);
    const int y1c = min(max(y1, 0), W - 1);
    int4 I;
    I.x = rowbase + y0c * W + x0c;
    I.y = rowbase + y0c * W + x1c;
    I.z = rowbase + y1c * W + x0c;
    I.w = rowbase + y1c * W + x1c;
    float4 Wv;
    Wv.x = aw * (1.f - dx) * (1.f - dy) * (mx0 * my0);
    Wv.y = aw * dx * (1.f - dy) * (mx1 * my0);
    Wv.z = aw * (1.f - dx) * dy * (mx0 * my1);
    Wv.w = aw * dx * dy * (mx1 * my1);
    const int pj = (j & ~15) | (tap ^ h);  // XOR-swizzle (h<8 -> flips low 3)
    *reinterpret_cast<int4*>(&sIdx[pj * 4]) = I;
    *reinterpret_cast<float4*>(&sW[pj * 4]) = Wv;
  }
  __syncthreads();

  // ---- phase 2: gather ----
  const int q  = threadIdx.x >> 6;         // 0..3
  const int h  = (threadIdx.x >> 3) & 7;   // 0..7
  const int dq = threadIdx.x & 7;          // 0..7 (covers 4 dims each)
  const float* vb = V + h * 32 + dq * 4;
  const int jbase = (q * 8 + h) * 16;
  f32x4 acc = (f32x4){0.f, 0.f, 0.f, 0.f};
#pragma unroll
  for (int tap = 0; tap < 16; ++tap) {
    const int pj = jbase + (tap ^ h);      // same swizzle as the write
    const int4   I  = *reinterpret_cast<const int4*>(&sIdx[pj * 4]);
    const float4 Wv = *reinterpret_cast<const float4*>(&sW[pj * 4]);
    const f32x4 v00 = *reinterpret_cast<const f32x4*>(vb + ((size_t)I.x << 8));
    const f32x4 v01 = *reinterpret_cast<const f32x4*>(vb + ((size_t)I.y << 8));
    const f32x4 v10 = *reinterpret_cast<const f32x4*>(vb + ((size_t)I.z << 8));
    const f32x4 v11 = *reinterpret_cast<const f32x4*>(vb + ((size_t)I.w << 8));
    acc += v00 * Wv.x;
    acc += v01 * Wv.y;
    acc += v10 * Wv.z;
    acc += v11 * Wv.w;
  }
  union { __hip_bfloat16 hh[4]; short4v v; } u;
  u.hh[0] = __float2bfloat16(acc.x);
  u.hh[1] = __float2bfloat16(acc.y);
  u.hh[2] = __float2bfloat16(acc.z);
  u.hh[3] = __float2bfloat16(acc.w);
  *reinterpret_cast<short4v*>(
      &ATT[(size_t)(bid0 + q) * 256 + h * 32 + dq * 4]) = u.v;
}

// ---------------- LayerNorm(T bf16) + add into out (out holds fused) --------
__global__ __launch_bounds__(256) void ln_add_kernel(
    const __hip_bfloat16* __restrict__ T, const float* __restrict__ lng,
    const float* __restrict__ lnb, float* __restrict__ out) {
  const size_t row = blockIdx.x;
  const int e = threadIdx.x;
  const float t = __bfloat162float(T[row * 256 + e]);
  float s = wred(t);
  float s2 = wred(t * t);
  __shared__ float red[8];
  const int wv = e >> 6;
  if ((e & 63) == 0) { red[wv] = s; red[4 + wv] = s2; }
  __syncthreads();
  const float S = red[0] + red[1] + red[2] + red[3];
  const float S2 = red[4] + red[5] + red[6] + red[7];
  const float mu = S * (1.f / 256.f);
  const float var = S2 * (1.f / 256.f) - mu * mu;
  const float y = (t - mu) * rsqrtf(var + 1e-5f) * lng[e] + lnb[e];
  out[row * 256 + e] += y;
}

extern "C" void kernel_launch(void* const* d_in, const int* in_sizes, int n_in,
                              void* d_out, int out_size, void* d_ws, size_t ws_size,
                              hipStream_t stream) {
  const float* Q  = (const float*)d_in[0];
  const float* g0 = (const float*)d_in[1];
  const float* g1 = (const float*)d_in[2];
  const float* g2 = (const float*)d_in[3];
  const float* g3 = (const float*)d_in[4];
  // d_in[5] = batch_size (fixed 4)
  const float* pw0 = (const float*)d_in[6];
  const float* pb0 = (const float*)d_in[7];
  const float* gg0 = (const float*)d_in[8];
  const float* gb0 = (const float*)d_in[9];
  const float* pw1 = (const float*)d_in[10];
  const float* pb1 = (const float*)d_in[11];
  const float* gg1 = (const float*)d_in[12];
  const float* gb1 = (const float*)d_in[13];
  const float* pw2 = (const float*)d_in[14];
  const float* pb2 = (const float*)d_in[15];
  const float* gg2 = (const float*)d_in[16];
  const float* gb2 = (const float*)d_in[17];
  const float* pw3 = (const float*)d_in[18];
  const float* pb3 = (const float*)d_in[19];
  const float* gg3 = (const float*)d_in[20];
  const float* gb3 = (const float*)d_in[21];
  const float* value_w = (const float*)d_in[22];
  const float* value_b = (const float*)d_in[23];
  const float* off_w   = (const float*)d_in[24];
  const float* off_b   = (const float*)d_in[25];
  const float* attw_w  = (const float*)d_in[26];
  const float* attw_b  = (const float*)d_in[27];
  const float* out_w   = (const float*)d_in[28];
  const float* out_b   = (const float*)d_in[29];
  const float* lin1_w  = (const float*)d_in[30];
  const float* lin1_b  = (const float*)d_in[31];
  const float* lin2_w  = (const float*)d_in[32];
  const float* lin2_b  = (const float*)d_in[33];
  const float* ln_g    = (const float*)d_in[34];
  const float* ln_b    = (const float*)d_in[35];

  char* ws = (char*)d_ws;
  __hip_bfloat16* WT_VALUE = (__hip_bfloat16*)(ws + 0);        // 131072
  __hip_bfloat16* WT_OFF   = (__hip_bfloat16*)(ws + 131072);   // 131072
  __hip_bfloat16* WT_ATTW  = (__hip_bfloat16*)(ws + 262144);   // 65536
  __hip_bfloat16* WT_OUT   = (__hip_bfloat16*)(ws + 327680);   // 131072
  __hip_bfloat16* WT_LIN1  = (__hip_bfloat16*)(ws + 458752);   // 262144
  __hip_bfloat16* WT_LIN2  = (__hip_bfloat16*)(ws + 720896);   // 262144 -> 983040
  __hip_bfloat16* WTP0     = (__hip_bfloat16*)(ws + 983040);   // 32768
  __hip_bfloat16* WTP1     = (__hip_bfloat16*)(ws + 1015808);  // 32768
  __hip_bfloat16* WTP2     = (__hip_bfloat16*)(ws + 1048576);  // 65536
  __hip_bfloat16* WTP3     = (__hip_bfloat16*)(ws + 1114112);  // 655360 -> 1769472
  __hip_bfloat16* XP0      = (__hip_bfloat16*)(ws + 1769472);  // 16384x64 -> 3866624
  __hip_bfloat16* XP1      = (__hip_bfloat16*)(ws + 3866624);  // 4096x64  -> 4390912
  __hip_bfloat16* XP2      = (__hip_bfloat16*)(ws + 4390912);  // 1024x128 -> 4653056
  __hip_bfloat16* XP3      = (__hip_bfloat16*)(ws + 4653056);  // 256x1280 -> 5308416
  float*          VAL      = (float*)(ws + 34406400);          // 22282240 -> 56688640
  __hip_bfloat16* VALB     = (__hip_bfloat16*)(ws + 23265280); // 11141120 -> 34406400
  float*          V        = (float*)(ws + 983040);            // 22282240 -> 23265280
  float*          AW       = (float*)(ws + 23265280);          // 33554432 -> 56819712
  __hip_bfloat16* ATT      = (__hip_bfloat16*)(ws + 56819712); // 33554432 -> 90374144 (peak)
  __hip_bfloat16* FUSEDB   = (__hip_bfloat16*)(ws + 983040);   // 33554432 -> 34537472
  __hip_bfloat16* HIDH     = (__hip_bfloat16*)(ws + 34537472); // 33554432 -> 68091904
  __hip_bfloat16* T16H     = (__hip_bfloat16*)(ws + 68091904); // 16777216 -> 84869120
  float*          OFFS     = (float*)d_out;                    // 64MB, dead before FUSED
  float*          FUSED    = (float*)d_out;                    // fused residual -> output

  // 1. weight transposes -> bf16 (N,K) (+ padded proj weights)
  tcast_kernel<<<256, 256, 0, stream>>>(value_w, WT_VALUE, 256, 256);
  tcast_kernel<<<256, 256, 0, stream>>>(off_w,   WT_OFF,   256, 256);
  tcast_kernel<<<128, 256, 0, stream>>>(attw_w,  WT_ATTW,  256, 128);
  tcast_kernel<<<256, 256, 0, stream>>>(out_w,   WT_OUT,   256, 256);
  tcast_kernel<<<512, 256, 0, stream>>>(lin1_w,  WT_LIN1,  256, 512);
  tcast_kernel<<<512, 256, 0, stream>>>(lin2_w,  WT_LIN2,  512, 256);
  tcast_pad_kernel<<<64,   256, 0, stream>>>(pw0, WTP0, 24,   64,   256);
  tcast_pad_kernel<<<64,   256, 0, stream>>>(pw1, WTP1, 40,   64,   256);
  tcast_pad_kernel<<<128,  256, 0, stream>>>(pw2, WTP2, 112,  128,  256);
  tcast_pad_kernel<<<1280, 256, 0, stream>>>(pw3, WTP3, 1280, 1280, 256);

  // 2. grd transpose/pad -> XP (bf16), element-parallel
  tpad_kernel<<<4096, 256, 0, stream>>>(g0, XP0, 24,   64,   4096, 16384 * 64);
  tpad_kernel<<<1024, 256, 0, stream>>>(g1, XP1, 40,   64,   1024, 4096 * 64);
  tpad_kernel<<<512,  256, 0, stream>>>(g2, XP2, 112,  128,  256,  1024 * 128);
  tpad_kernel<<<1280, 256, 0, stream>>>(g3, XP3, 1280, 1280, 64,   256 * 1280);

  // 3. proj GEMMs -> VAL (level-major) ; GN -> VALB ; value GEMM -> V (f32)
  gemm_bt<0, false><<<dim3(128, 2), 256, 0, stream>>>(XP0, WTP0, pb0, VAL,
                                                      nullptr, nullptr, 16384, 256, 64);
  gemm_bt<0, false><<<dim3(32, 2), 256, 0, stream>>>(XP1, WTP1, pb1, VAL + (size_t)16384 * 256,
                                                     nullptr, nullptr, 4096, 256, 64);
  gemm_bt<0, false><<<dim3(8, 2), 256, 0, stream>>>(XP2, WTP2, pb2, VAL + (size_t)20480 * 256,
                                                    nullptr, nullptr, 1024, 256, 128);
  gemm_bt<0, false><<<dim3(2, 2), 256, 0, stream>>>(XP3, WTP3, pb3, VAL + (size_t)21504 * 256,
                                                    nullptr, nullptr, 256, 256, 1280);
  gn_kernel<<<512, 256, 0, stream>>>(VAL, VALB, gg0, gb0, gg1, gb1, gg2, gb2, gg3, gb3);
  gemm_bt<0, false><<<dim3(170, 2), 256, 0, stream>>>(VALB, WT_VALUE, value_b, V,
                                                      nullptr, nullptr, 21760, 256, 256);

  // 4. query branch: offsets (-> d_out) + attention weights (+softmax); X = Q fp32
  gemm_bt<0, true><<<dim3(512, 2), 256, 0, stream>>>(Q, WT_OFF, off_b, OFFS,
                                                     nullptr, nullptr, 65536, 256, 256);
  gemm_bt<0, true><<<dim3(512, 1), 256, 0, stream>>>(Q, WT_ATTW, attw_b, AW,
                                                     nullptr, nullptr, 65536, 128, 256);
  softmax_kernel<<<2048, 256, 0, stream>>>(AW);

  // 5. deformable sampling -> ATT (bf16)
  sampler_kernel<<<16384, 256, 0, stream>>>(V, OFFS, AW, ATT);

  // 6. out proj + 2Q residual: FUSED(f32, d_out; kills OFFS) + FUSEDB(bf16)
  gemm_bt<2, false><<<dim3(512, 2), 256, 0, stream>>>(ATT, WT_OUT, out_b, FUSED,
                                                      FUSEDB, Q, 65536, 256, 256);

  // 7. FFN in two M-halves of 32768 rows:
  //    lin1(relu)->HIDH, lin2->T16H bf16, LN+add into FUSED.
  for (int h = 0; h < 2; ++h) {
    const __hip_bfloat16* Xh = FUSEDB + (size_t)h * 32768 * 256;
    gemm_bt<1, false><<<dim3(256, 4), 256, 0, stream>>>(Xh, WT_LIN1, lin1_b, nullptr,
                                                        HIDH, nullptr, 32768, 512, 256);
    gemm_bt<3, false><<<dim3(256, 2), 256, 0, stream>>>(HIDH, WT_LIN2, lin2_b, nullptr,
                                                        T16H, nullptr, 32768, 256, 512);
    ln_add_kernel<<<32768, 256, 0, stream>>>(T16H, ln_g, ln_b,
                                             FUSED + (size_t)h * 32768 * 256);
  }
}

// Round 8
// 669.034 us; speedup vs baseline: 1.0174x; 1.0174x over previous
//
#include <hip/hip_runtime.h>
#include <hip/hip_bf16.h>

// deformable_cross_grd_attention — MI355X/gfx950
// B=4, NQ=16384, EMBED=256, HEADS=8, HEAD_DIM=32, LEVELS=4, POINTS=4, NV=5440
//
// r7 changes: (1) value matrix VB kept in bf16 -> sampler gather bytes/requests
// halved (was at the L2 ~31 TB/s ceiling); (2) softmax fused into sampler
// phase 1 (16-lane shfl reduce); (3) weight-prep 10 kernels -> 1, tpad 4 -> 1
// (28 -> 18 dispatches).
//
// VAL/VALB/VB rows are LEVEL-MAJOR: row = startB[l] + b*HW_l + hw,
// startB = {0, 16384, 20480, 21504} (rows), 21760 rows total.
//
// Workspace overlay timeline (PEAK = 90,374,144 B, proven r4-r7):
//   [0, 983040)          WT_*/WTP* bf16 weights — live whole launch
//   [1769472, 5308416)   XP0..3 — dead after proj GEMMs
//   [34406400, 56688640) VAL f32 — dead after GN
//   [23265280, 34406400) VALB bf16 — dead after value GEMM
//   [983040, 12124160)   VB bf16 — dead after sampler
//   [23265280, 56819712) AWr f32 (raw scores) — overlays dead VALB+VAL
//   [56819712, 90374144) ATT bf16 — sampler -> out GEMM
//   [983040, 34537472)   FUSEDB bf16 — overlays dead VB/AWr-head
//   [34537472, 68091904) HIDH bf16 — per FFN half
//   [68091904, 84869120) T16H bf16 — per FFN half
//   OFFS f32 (64MB) = d_out; dead before out-GEMM writes FUSED there.

#define NQc 16384
#define NVc 5440

typedef __attribute__((ext_vector_type(8))) short short8;
typedef __attribute__((ext_vector_type(4))) short short4v;
typedef __attribute__((ext_vector_type(4))) float f32x4;

// global_load_lds: 16B per lane, LDS dest = wave-uniform base + lane*16.
#define GLOAD16(gp, lp)                                                        \
  __builtin_amdgcn_global_load_lds(                                           \
      (const __attribute__((address_space(1))) unsigned int*)(gp),            \
      (__attribute__((address_space(3))) unsigned int*)(lp), 16, 0, 0)

__device__ __forceinline__ float wred(float v) {
#pragma unroll
  for (int o = 32; o > 0; o >>= 1) v += __shfl_down(v, o);
  return v;
}

__device__ __forceinline__ float b2f(unsigned short u) {
  union { unsigned int i; float f; } c;
  c.i = ((unsigned int)u) << 16;
  return c.f;
}

// ---------- consolidated weight prep: transpose+cast(+pad) all 10 weights ----
// dst[n*Kp+k] = k<K ? bf16(src[k*N+n]) : 0.  Segment bounds are 256-multiples,
// so every block lies in exactly one segment.
__global__ __launch_bounds__(256) void prep_kernel(
    const float* s0, const float* s1, const float* s2, const float* s3,
    const float* s4, const float* s5, const float* s6, const float* s7,
    const float* s8, const float* s9,
    __hip_bfloat16* d0, __hip_bfloat16* d1, __hip_bfloat16* d2,
    __hip_bfloat16* d3, __hip_bfloat16* d4, __hip_bfloat16* d5,
    __hip_bfloat16* d6, __hip_bfloat16* d7, __hip_bfloat16* d8,
    __hip_bfloat16* d9) {
  const int i = blockIdx.x * 256 + threadIdx.x;
#define SEG(lo, hi, K, Kp, N, src, dst)                                        \
  if (i < (hi)) {                                                              \
    const int j = i - (lo);                                                    \
    const int n = j / (Kp), k = j - n * (Kp);                                  \
    dst[j] = (k < (K)) ? __float2bfloat16(src[k * (N) + n])                    \
                       : __float2bfloat16(0.f);                                \
    return;                                                                    \
  }
  SEG(0,      65536,  256,  256,  256, s0, d0)   // value_w -> WT_VALUE
  SEG(65536,  131072, 256,  256,  256, s1, d1)   // off_w   -> WT_OFF
  SEG(131072, 163840, 256,  256,  128, s2, d2)   // attw_w  -> WT_ATTW
  SEG(163840, 229376, 256,  256,  256, s3, d3)   // out_w   -> WT_OUT
  SEG(229376, 360448, 256,  256,  512, s4, d4)   // lin1_w  -> WT_LIN1
  SEG(360448, 491520, 512,  512,  256, s5, d5)   // lin2_w  -> WT_LIN2
  SEG(491520, 507904, 24,   64,   256, s6, d6)   // pw0     -> WTP0
  SEG(507904, 524288, 40,   64,   256, s7, d7)   // pw1     -> WTP1
  SEG(524288, 557056, 112,  128,  256, s8, d8)   // pw2     -> WTP2
  SEG(557056, 884736, 1280, 1280, 256, s9, d9)   // pw3     -> WTP3
#undef SEG
}

// ---------- consolidated grd transpose+cast+pad (element-parallel) ----------
__global__ __launch_bounds__(256) void tpad_all_kernel(
    const float* g0, const float* g1, const float* g2, const float* g3,
    __hip_bfloat16* x0, __hip_bfloat16* x1, __hip_bfloat16* x2,
    __hip_bfloat16* x3) {
  const int i = blockIdx.x * 256 + threadIdx.x;
#define TSEG(lo, hi, C, Kp, HW, src, dst)                                      \
  if (i < (hi)) {                                                              \
    const int j = i - (lo);                                                    \
    const int row = j / (Kp);                                                  \
    const int k = j - row * (Kp);                                              \
    const int b = row / (HW);                                                  \
    const int hw = row - b * (HW);                                             \
    dst[j] = (k < (C))                                                         \
        ? __float2bfloat16(src[((size_t)b * (C) + k) * (HW) + hw])             \
        : __float2bfloat16(0.f);                                               \
    return;                                                                    \
  }
  TSEG(0,       1048576, 24,   64,   4096, g0, x0)
  TSEG(1048576, 1310720, 40,   64,   1024, g1, x1)
  TSEG(1310720, 1441792, 112,  128,  256,  g2, x2)
  TSEG(1441792, 1769472, 1280, 1280, 64,   g3, x3)
#undef TSEG
}

// ---------------- GroupNorm (32 groups of 8 ch) -> bf16, level-major --------
__global__ __launch_bounds__(256) void gn_kernel(
    const float* __restrict__ val, __hip_bfloat16* __restrict__ valb,
    const float* __restrict__ gg0, const float* __restrict__ gb0,
    const float* __restrict__ gg1, const float* __restrict__ gb1,
    const float* __restrict__ gg2, const float* __restrict__ gb2,
    const float* __restrict__ gg3, const float* __restrict__ gb3) {
  const int bid = blockIdx.x;            // b*128 + l*32 + grp
  const int grp = bid & 31;
  const int l = (bid >> 5) & 3;
  const int b = bid >> 7;
  int HW, startB; const float *gg, *gbeta;
  if (l == 0)      { HW = 4096; startB = 0;     gg = gg0; gbeta = gb0; }
  else if (l == 1) { HW = 1024; startB = 16384; gg = gg1; gbeta = gb1; }
  else if (l == 2) { HW = 256;  startB = 20480; gg = gg2; gbeta = gb2; }
  else             { HW = 64;   startB = 21504; gg = gg3; gbeta = gb3; }
  const int n = HW * 8;
  const size_t base = ((size_t)(startB + b * HW)) * 256 + grp * 8;
  float s = 0.f, s2 = 0.f;
  for (int i = threadIdx.x; i < n; i += 256) {
    float x = val[base + (size_t)(i >> 3) * 256 + (i & 7)];
    s += x; s2 += x * x;
  }
  s = wred(s); s2 = wred(s2);
  __shared__ float red[8];
  const int wv = threadIdx.x >> 6;
  if ((threadIdx.x & 63) == 0) { red[wv] = s; red[4 + wv] = s2; }
  __syncthreads();
  const float S = red[0] + red[1] + red[2] + red[3];
  const float S2 = red[4] + red[5] + red[6] + red[7];
  const float inv_n = 1.f / (float)n;
  const float mu = S * inv_n;
  const float var = S2 * inv_n - mu * mu;
  const float rstd = rsqrtf(var + 1e-5f);
  for (int i = threadIdx.x; i < n; i += 256) {
    const int j = i & 7;
    const int e = grp * 8 + j;
    const size_t idx = base + (size_t)(i >> 3) * 256 + j;
    const float y = (val[idx] - mu) * rstd * gg[e] + gbeta[e];
    valb[idx] = __float2bfloat16(y);
  }
}

// ---------------- bf16 MFMA GEMM: C[M][N] = X[M][K] * Wt[N][K]^T + bias ------
// 128x128 tile, BK=64, 4 waves (2x2), 4x4 16x16x32 frags per wave.
// !XF32: As/Bs staged via global_load_lds (16B/lane, linear LDS).
// XF32: X fp32, converted to bf16 during reg staging.
// MODE 0: Cf=f32(acc+bias)  1: Cb=bf16(relu)  2: +2Q dual-write  3: Cb=bf16
template <int MODE, bool XF32>
__global__ __launch_bounds__(256) void gemm_bt(
    const void* __restrict__ Xv, const __hip_bfloat16* __restrict__ Wt,
    const float* __restrict__ bias, float* __restrict__ Cf,
    __hip_bfloat16* __restrict__ Cb, const float* __restrict__ Qres,
    int M, int N, int K) {
  const int m0 = blockIdx.x * 128;
  const int n0 = blockIdx.y * 128;
  const int tid = threadIdx.x;
  const int wave = tid >> 6;
  const int lane = tid & 63;
  const int wm = wave >> 1;
  const int wn = wave & 1;
  const int l15 = lane & 15;
  const int l4 = lane >> 4;
  __shared__ __align__(16) __hip_bfloat16 As[128 * 64];
  __shared__ __align__(16) __hip_bfloat16 Bs[128 * 64];
  f32x4 acc[4][4];
#pragma unroll
  for (int m = 0; m < 4; ++m)
#pragma unroll
    for (int n = 0; n < 4; ++n) acc[m][n] = (f32x4){0.f, 0.f, 0.f, 0.f};

  for (int k0 = 0; k0 < K; k0 += 64) {
#pragma unroll
    for (int j = 0; j < 4; ++j) {
      const int e = (j * 256 + tid) * 8;
      const int r = e >> 6;
      const int k = e & 63;
      if constexpr (XF32) {
        const float* Xf = (const float*)Xv;
        const float4 a = *reinterpret_cast<const float4*>(&Xf[(size_t)(m0 + r) * K + k0 + k]);
        const float4 b = *reinterpret_cast<const float4*>(&Xf[(size_t)(m0 + r) * K + k0 + k + 4]);
        union { __hip_bfloat16 h[8]; short8 v; } u;
        u.h[0] = __float2bfloat16(a.x); u.h[1] = __float2bfloat16(a.y);
        u.h[2] = __float2bfloat16(a.z); u.h[3] = __float2bfloat16(a.w);
        u.h[4] = __float2bfloat16(b.x); u.h[5] = __float2bfloat16(b.y);
        u.h[6] = __float2bfloat16(b.z); u.h[7] = __float2bfloat16(b.w);
        *reinterpret_cast<short8*>(&As[e]) = u.v;
        *reinterpret_cast<short8*>(&Bs[e]) =
            *reinterpret_cast<const short8*>(&Wt[(size_t)(n0 + r) * K + k0 + k]);
      } else {
        const __hip_bfloat16* Xb = (const __hip_bfloat16*)Xv;
        GLOAD16(&Xb[(size_t)(m0 + r) * K + k0 + k], &As[e]);
        GLOAD16(&Wt[(size_t)(n0 + r) * K + k0 + k], &Bs[e]);
      }
    }
    __syncthreads();
#pragma unroll
    for (int ks = 0; ks < 2; ++ks) {
      short8 a[4], bfr[4];
#pragma unroll
      for (int m = 0; m < 4; ++m)
        a[m] = *reinterpret_cast<const short8*>(
            &As[(wm * 64 + m * 16 + l15) * 64 + ks * 32 + l4 * 8]);
#pragma unroll
      for (int n = 0; n < 4; ++n)
        bfr[n] = *reinterpret_cast<const short8*>(
            &Bs[(wn * 64 + n * 16 + l15) * 64 + ks * 32 + l4 * 8]);
#pragma unroll
      for (int m = 0; m < 4; ++m)
#pragma unroll
        for (int n = 0; n < 4; ++n)
          acc[m][n] = __builtin_amdgcn_mfma_f32_16x16x32_bf16(a[m], bfr[n], acc[m][n], 0, 0, 0);
    }
    __syncthreads();
  }

#pragma unroll
  for (int m = 0; m < 4; ++m) {
    const int row0 = m0 + wm * 64 + m * 16 + l4 * 4;
#pragma unroll
    for (int n = 0; n < 4; ++n) {
      const int col = n0 + wn * 64 + n * 16 + l15;
      const float bv = bias[col];
#pragma unroll
      for (int r = 0; r < 4; ++r) {
        const size_t ci = (size_t)(row0 + r) * N + col;
        float f = acc[m][n][r] + bv;
        if (MODE == 0) {
          Cf[ci] = f;
        } else if (MODE == 1) {
          Cb[ci] = __float2bfloat16(fmaxf(f, 0.f));
        } else if (MODE == 2) {
          f += 2.f * Qres[ci];
          Cf[ci] = f;
          Cb[ci] = __float2bfloat16(f);
        } else {
          Cb[ci] = __float2bfloat16(f);
        }
      }
    }
  }
}

// ---------------- deformable bilinear sampler (2-phase, fused softmax) ------
// block = 4 queries; 256 threads. VB is bf16, level-major:
// row = startB[l]+b*HW_l+pos. Softmax over the 16 taps of one (q,h) is done
// in-register via 16-lane shfl_xor (taps are 16 consecutive lanes).
// LDS entries XOR-swizzled (tap^h) to keep phase-2 reads conflict-free.
__global__ __launch_bounds__(256) void sampler_kernel(
    const __hip_bfloat16* __restrict__ VB, const float* __restrict__ OFFS,
    const float* __restrict__ AWr, __hip_bfloat16* __restrict__ ATT) {
  __shared__ int   sIdx[512 * 4];
  __shared__ float sW[512 * 4];
  const int blk = blockIdx.x;              // [0, B*NQ/4)
  const int b = blk >> 12;                 // NQ/4 = 4096 blocks per batch
  const int q0 = (blk & 4095) << 2;        // within-batch first query
  const int bid0 = blk << 2;               // global row (b*NQ + q0)

  // ---- phase 1: geometry + softmax ----
  for (int j = threadIdx.x; j < 512; j += 256) {
    const int q   = j >> 7;                // 0..3
    const int h   = (j >> 4) & 7;
    const int tap = j & 15;                // l*4 + p
    const int l = tap >> 2;
    const int gq = bid0 + q;
    const int qq = q0 + q;
    const float rx = (float)(qq & 127) * (1.f / 127.f);
    const float ry = (float)(qq >> 7) * (1.f / 127.f);
    const float2 oxy = *reinterpret_cast<const float2*>(
        &OFFS[(size_t)gq * 256 + h * 32 + tap * 2]);
    const float s_raw = AWr[(size_t)gq * 128 + h * 16 + tap];
    // softmax over 16-lane tap group (lanes j..j^15 share (q,h))
    float mx = s_raw;
#pragma unroll
    for (int o = 1; o < 16; o <<= 1) mx = fmaxf(mx, __shfl_xor(mx, o));
    const float ex = __expf(s_raw - mx);
    float sum = ex;
#pragma unroll
    for (int o = 1; o < 16; o <<= 1) sum += __shfl_xor(sum, o);
    const float aw = ex / sum;

    const int W = 64 >> l;
    const int HWl = W * W;
    const int startB = (l == 0) ? 0 : (l == 1) ? 16384 : (l == 2) ? 20480 : 21504;
    const int rowbase = startB + b * HWl;
    const float fW = (float)W;
    const float x = rx * fW + oxy.x - 0.5f;
    const float y = ry * fW + oxy.y - 0.5f;
    const float x0f = floorf(x);
    const float y0f = floorf(y);
    const int x0 = (int)x0f;
    const int y0 = (int)y0f;
    const float dx = x - x0f;
    const float dy = y - y0f;
    const int x1 = x0 + 1, y1 = y0 + 1;
    const float mx0 = (x0 >= 0 && x0 < W) ? 1.f : 0.f;
    const float mx1 = (x1 >= 0 && x1 < W) ? 1.f : 0.f;
    const float my0 = (y0 >= 0 && y0 < W) ? 1.f : 0.f;
    const float my1 = (y1 >= 0 && y1 < W) ? 1.f : 0.f;
    const int x0c = min(max(x0, 0), W - 1);
    const int x1c = min(max(x1, 0), W - 1);
    const int y0c = min(max(y0, 0), W - 1);
    const int y1c = min(max(y1, 0), W - 1);
    int4 I;
    I.x = rowbase + y0c * W + x0c;
    I.y = rowbase + y0c * W + x1c;
    I.z = rowbase + y1c * W + x0c;
    I.w = rowbase + y1c * W + x1c;
    float4 Wv;
    Wv.x = aw * (1.f - dx) * (1.f - dy) * (mx0 * my0);
    Wv.y = aw * dx * (1.f - dy) * (mx1 * my0);
    Wv.z = aw * (1.f - dx) * dy * (mx0 * my1);
    Wv.w = aw * dx * dy * (mx1 * my1);
    const int pj = (j & ~15) | (tap ^ h);  // XOR-swizzle
    *reinterpret_cast<int4*>(&sIdx[pj * 4]) = I;
    *reinterpret_cast<float4*>(&sW[pj * 4]) = Wv;
  }
  __syncthreads();

  // ---- phase 2: bf16 gather (8B/lane) ----
  const int q  = threadIdx.x >> 6;         // 0..3
  const int h  = (threadIdx.x >> 3) & 7;   // 0..7
  const int dq = threadIdx.x & 7;          // 0..7 (covers 4 dims each)
  const __hip_bfloat16* vb = VB + h * 32 + dq * 4;
  const int jbase = (q * 8 + h) * 16;
  f32x4 acc = (f32x4){0.f, 0.f, 0.f, 0.f};
#pragma unroll
  for (int tap = 0; tap < 16; ++tap) {
    const int pj = jbase + (tap ^ h);      // same swizzle as the write
    const int4   I  = *reinterpret_cast<const int4*>(&sIdx[pj * 4]);
    const float4 Wv = *reinterpret_cast<const float4*>(&sW[pj * 4]);
    const short4v r00 = *reinterpret_cast<const short4v*>(vb + ((size_t)I.x << 8));
    const short4v r01 = *reinterpret_cast<const short4v*>(vb + ((size_t)I.y << 8));
    const short4v r10 = *reinterpret_cast<const short4v*>(vb + ((size_t)I.z << 8));
    const short4v r11 = *reinterpret_cast<const short4v*>(vb + ((size_t)I.w << 8));
#pragma unroll
    for (int d = 0; d < 4; ++d) {
      acc[d] += b2f((unsigned short)r00[d]) * Wv.x +
                b2f((unsigned short)r01[d]) * Wv.y +
                b2f((unsigned short)r10[d]) * Wv.z +
                b2f((unsigned short)r11[d]) * Wv.w;
    }
  }
  union { __hip_bfloat16 hh[4]; short4v v; } u;
  u.hh[0] = __float2bfloat16(acc[0]);
  u.hh[1] = __float2bfloat16(acc[1]);
  u.hh[2] = __float2bfloat16(acc[2]);
  u.hh[3] = __float2bfloat16(acc[3]);
  *reinterpret_cast<short4v*>(
      &ATT[(size_t)(bid0 + q) * 256 + h * 32 + dq * 4]) = u.v;
}

// ---------------- LayerNorm(T bf16) + add into out (out holds fused) --------
__global__ __launch_bounds__(256) void ln_add_kernel(
    const __hip_bfloat16* __restrict__ T, const float* __restrict__ lng,
    const float* __restrict__ lnb, float* __restrict__ out) {
  const size_t row = blockIdx.x;
  const int e = threadIdx.x;
  const float t = __bfloat162float(T[row * 256 + e]);
  float s = wred(t);
  float s2 = wred(t * t);
  __shared__ float red[8];
  const int wv = e >> 6;
  if ((e & 63) == 0) { red[wv] = s; red[4 + wv] = s2; }
  __syncthreads();
  const float S = red[0] + red[1] + red[2] + red[3];
  const float S2 = red[4] + red[5] + red[6] + red[7];
  const float mu = S * (1.f / 256.f);
  const float var = S2 * (1.f / 256.f) - mu * mu;
  const float y = (t - mu) * rsqrtf(var + 1e-5f) * lng[e] + lnb[e];
  out[row * 256 + e] += y;
}

extern "C" void kernel_launch(void* const* d_in, const int* in_sizes, int n_in,
                              void* d_out, int out_size, void* d_ws, size_t ws_size,
                              hipStream_t stream) {
  const float* Q  = (const float*)d_in[0];
  const float* g0 = (const float*)d_in[1];
  const float* g1 = (const float*)d_in[2];
  const float* g2 = (const float*)d_in[3];
  const float* g3 = (const float*)d_in[4];
  // d_in[5] = batch_size (fixed 4)
  const float* pw0 = (const float*)d_in[6];
  const float* pb0 = (const float*)d_in[7];
  const float* gg0 = (const float*)d_in[8];
  const float* gb0 = (const float*)d_in[9];
  const float* pw1 = (const float*)d_in[10];
  const float* pb1 = (const float*)d_in[11];
  const float* gg1 = (const float*)d_in[12];
  const float* gb1 = (const float*)d_in[13];
  const float* pw2 = (const float*)d_in[14];
  const float* pb2 = (const float*)d_in[15];
  const float* gg2 = (const float*)d_in[16];
  const float* gb2 = (const float*)d_in[17];
  const float* pw3 = (const float*)d_in[18];
  const float* pb3 = (const float*)d_in[19];
  const float* gg3 = (const float*)d_in[20];
  const float* gb3 = (const float*)d_in[21];
  const float* value_w = (const float*)d_in[22];
  const float* value_b = (const float*)d_in[23];
  const float* off_w   = (const float*)d_in[24];
  const float* off_b   = (const float*)d_in[25];
  const float* attw_w  = (const float*)d_in[26];
  const float* attw_b  = (const float*)d_in[27];
  const float* out_w   = (const float*)d_in[28];
  const float* out_b   = (const float*)d_in[29];
  const float* lin1_w  = (const float*)d_in[30];
  const float* lin1_b  = (const float*)d_in[31];
  const float* lin2_w  = (const float*)d_in[32];
  const float* lin2_b  = (const float*)d_in[33];
  const float* ln_g    = (const float*)d_in[34];
  const float* ln_b    = (const float*)d_in[35];

  char* ws = (char*)d_ws;
  __hip_bfloat16* WT_VALUE = (__hip_bfloat16*)(ws + 0);        // 131072
  __hip_bfloat16* WT_OFF   = (__hip_bfloat16*)(ws + 131072);   // 131072
  __hip_bfloat16* WT_ATTW  = (__hip_bfloat16*)(ws + 262144);   // 65536
  __hip_bfloat16* WT_OUT   = (__hip_bfloat16*)(ws + 327680);   // 131072
  __hip_bfloat16* WT_LIN1  = (__hip_bfloat16*)(ws + 458752);   // 262144
  __hip_bfloat16* WT_LIN2  = (__hip_bfloat16*)(ws + 720896);   // 262144 -> 983040
  __hip_bfloat16* WTP0     = (__hip_bfloat16*)(ws + 983040);   // 32768
  __hip_bfloat16* WTP1     = (__hip_bfloat16*)(ws + 1015808);  // 32768
  __hip_bfloat16* WTP2     = (__hip_bfloat16*)(ws + 1048576);  // 65536
  __hip_bfloat16* WTP3     = (__hip_bfloat16*)(ws + 1114112);  // 655360 -> 1769472
  __hip_bfloat16* XP0      = (__hip_bfloat16*)(ws + 1769472);  // -> 3866624
  __hip_bfloat16* XP1      = (__hip_bfloat16*)(ws + 3866624);  // -> 4390912
  __hip_bfloat16* XP2      = (__hip_bfloat16*)(ws + 4390912);  // -> 4653056
  __hip_bfloat16* XP3      = (__hip_bfloat16*)(ws + 4653056);  // -> 5308416
  float*          VAL      = (float*)(ws + 34406400);          // -> 56688640
  __hip_bfloat16* VALB     = (__hip_bfloat16*)(ws + 23265280); // -> 34406400
  __hip_bfloat16* VB       = (__hip_bfloat16*)(ws + 983040);   // bf16 value -> 12124160
  float*          AWr      = (float*)(ws + 23265280);          // raw scores -> 56819712
  __hip_bfloat16* ATT      = (__hip_bfloat16*)(ws + 56819712); // -> 90374144 (peak)
  __hip_bfloat16* FUSEDB   = (__hip_bfloat16*)(ws + 983040);   // -> 34537472
  __hip_bfloat16* HIDH     = (__hip_bfloat16*)(ws + 34537472); // -> 68091904
  __hip_bfloat16* T16H     = (__hip_bfloat16*)(ws + 68091904); // -> 84869120
  float*          OFFS     = (float*)d_out;                    // 64MB, dead before FUSED
  float*          FUSED    = (float*)d_out;                    // fused residual -> output

  // 1. all weight prep in one launch
  prep_kernel<<<3456, 256, 0, stream>>>(value_w, off_w, attw_w, out_w, lin1_w,
                                        lin2_w, pw0, pw1, pw2, pw3,
                                        WT_VALUE, WT_OFF, WT_ATTW, WT_OUT,
                                        WT_LIN1, WT_LIN2, WTP0, WTP1, WTP2, WTP3);

  // 2. grd transpose/pad in one launch
  tpad_all_kernel<<<6912, 256, 0, stream>>>(g0, g1, g2, g3, XP0, XP1, XP2, XP3);

  // 3. proj GEMMs -> VAL (level-major) ; GN -> VALB ; value GEMM -> VB (bf16)
  gemm_bt<0, false><<<dim3(128, 2), 256, 0, stream>>>(XP0, WTP0, pb0, VAL,
                                                      nullptr, nullptr, 16384, 256, 64);
  gemm_bt<0, false><<<dim3(32, 2), 256, 0, stream>>>(XP1, WTP1, pb1, VAL + (size_t)16384 * 256,
                                                     nullptr, nullptr, 4096, 256, 64);
  gemm_bt<0, false><<<dim3(8, 2), 256, 0, stream>>>(XP2, WTP2, pb2, VAL + (size_t)20480 * 256,
                                                    nullptr, nullptr, 1024, 256, 128);
  gemm_bt<0, false><<<dim3(2, 2), 256, 0, stream>>>(XP3, WTP3, pb3, VAL + (size_t)21504 * 256,
                                                    nullptr, nullptr, 256, 256, 1280);
  gn_kernel<<<512, 256, 0, stream>>>(VAL, VALB, gg0, gb0, gg1, gb1, gg2, gb2, gg3, gb3);
  gemm_bt<3, false><<<dim3(170, 2), 256, 0, stream>>>(VALB, WT_VALUE, value_b, nullptr,
                                                      VB, nullptr, 21760, 256, 256);

  // 4. query branch: offsets (-> d_out) + raw attention scores; X = Q fp32
  gemm_bt<0, true><<<dim3(512, 2), 256, 0, stream>>>(Q, WT_OFF, off_b, OFFS,
                                                     nullptr, nullptr, 65536, 256, 256);
  gemm_bt<0, true><<<dim3(512, 1), 256, 0, stream>>>(Q, WT_ATTW, attw_b, AWr,
                                                     nullptr, nullptr, 65536, 128, 256);

  // 5. deformable sampling (softmax fused) -> ATT (bf16)
  sampler_kernel<<<16384, 256, 0, stream>>>(VB, OFFS, AWr, ATT);

  // 6. out proj + 2Q residual: FUSED(f32, d_out; kills OFFS) + FUSEDB(bf16)
  gemm_bt<2, false><<<dim3(512, 2), 256, 0, stream>>>(ATT, WT_OUT, out_b, FUSED,
                                                      FUSEDB, Q, 65536, 256, 256);

  // 7. FFN in two M-halves of 32768 rows:
  //    lin1(relu)->HIDH, lin2->T16H bf16, LN+add into FUSED.
  for (int h = 0; h < 2; ++h) {
    const __hip_bfloat16* Xh = FUSEDB + (size_t)h * 32768 * 256;
    gemm_bt<1, false><<<dim3(256, 4), 256, 0, stream>>>(Xh, WT_LIN1, lin1_b, nullptr,
                                                        HIDH, nullptr, 32768, 512, 256);
    gemm_bt<3, false><<<dim3(256, 2), 256, 0, stream>>>(HIDH, WT_LIN2, lin2_b, nullptr,
                                                        T16H, nullptr, 32768, 256, 512);
    ln_add_kernel<<<32768, 256, 0, stream>>>(T16H, ln_g, ln_b,
                                             FUSED + (size_t)h * 32768 * 256);
  }
}

// Round 9
// 637.684 us; speedup vs baseline: 1.0674x; 1.0492x over previous
//
#include <hip/hip_runtime.h>
#include <hip/hip_bf16.h>

// deformable_cross_grd_attention — MI355X/gfx950
// B=4, NQ=16384, EMBED=256, HEADS=8, HEAD_DIM=32, LEVELS=4, POINTS=4, NV=5440
//
// r8 lesson: sampler at 68 VGPR crossed the 64-VGPR occupancy cliff (waves/SIMD
// halve, m69) -> occupancy 83%->32%, gather latency-bound, 174us. r9: force
// <=64 VGPR via __launch_bounds__(256,8), partial unroll, lean bf16 unpack.
//
// VAL/VALB/VB rows are LEVEL-MAJOR: row = startB[l] + b*HW_l + hw,
// startB = {0, 16384, 20480, 21504} (rows), 21760 rows total.
//
// Workspace overlay timeline (PEAK = 90,374,144 B, proven r4-r8):
//   [0, 983040)          WT_*/WTP* bf16 weights — live whole launch
//   [1769472, 5308416)   XP0..3 — dead after proj GEMMs
//   [34406400, 56688640) VAL f32 — dead after GN
//   [23265280, 34406400) VALB bf16 — dead after value GEMM
//   [983040, 12124160)   VB bf16 — dead after sampler
//   [23265280, 56819712) AWr f32 (raw scores) — overlays dead VALB+VAL
//   [56819712, 90374144) ATT bf16 — sampler -> out GEMM
//   [983040, 34537472)   FUSEDB bf16 — overlays dead VB/AWr-head
//   [34537472, 68091904) HIDH bf16 — per FFN half
//   [68091904, 84869120) T16H bf16 — per FFN half
//   OFFS f32 (64MB) = d_out; dead before out-GEMM writes FUSED there.

#define NQc 16384
#define NVc 5440

typedef __attribute__((ext_vector_type(8))) short short8;
typedef __attribute__((ext_vector_type(4))) short short4v;
typedef __attribute__((ext_vector_type(4))) float f32x4;
typedef unsigned int u32;

// global_load_lds: 16B per lane, LDS dest = wave-uniform base + lane*16.
#define GLOAD16(gp, lp)                                                        \
  __builtin_amdgcn_global_load_lds(                                           \
      (const __attribute__((address_space(1))) unsigned int*)(gp),            \
      (__attribute__((address_space(3))) unsigned int*)(lp), 16, 0, 0)

__device__ __forceinline__ float wred(float v) {
#pragma unroll
  for (int o = 32; o > 0; o >>= 1) v += __shfl_down(v, o);
  return v;
}

__device__ __forceinline__ float blo(u32 u) {
  union { u32 i; float f; } c; c.i = u << 16; return c.f;
}
__device__ __forceinline__ float bhi(u32 u) {
  union { u32 i; float f; } c; c.i = u & 0xffff0000u; return c.f;
}

// ---------- consolidated weight prep: transpose+cast(+pad) all 10 weights ----
__global__ __launch_bounds__(256) void prep_kernel(
    const float* s0, const float* s1, const float* s2, const float* s3,
    const float* s4, const float* s5, const float* s6, const float* s7,
    const float* s8, const float* s9,
    __hip_bfloat16* d0, __hip_bfloat16* d1, __hip_bfloat16* d2,
    __hip_bfloat16* d3, __hip_bfloat16* d4, __hip_bfloat16* d5,
    __hip_bfloat16* d6, __hip_bfloat16* d7, __hip_bfloat16* d8,
    __hip_bfloat16* d9) {
  const int i = blockIdx.x * 256 + threadIdx.x;
#define SEG(lo, hi, K, Kp, N, src, dst)                                        \
  if (i < (hi)) {                                                              \
    const int j = i - (lo);                                                    \
    const int n = j / (Kp), k = j - n * (Kp);                                  \
    dst[j] = (k < (K)) ? __float2bfloat16(src[k * (N) + n])                    \
                       : __float2bfloat16(0.f);                                \
    return;                                                                    \
  }
  SEG(0,      65536,  256,  256,  256, s0, d0)   // value_w -> WT_VALUE
  SEG(65536,  131072, 256,  256,  256, s1, d1)   // off_w   -> WT_OFF
  SEG(131072, 163840, 256,  256,  128, s2, d2)   // attw_w  -> WT_ATTW
  SEG(163840, 229376, 256,  256,  256, s3, d3)   // out_w   -> WT_OUT
  SEG(229376, 360448, 256,  256,  512, s4, d4)   // lin1_w  -> WT_LIN1
  SEG(360448, 491520, 512,  512,  256, s5, d5)   // lin2_w  -> WT_LIN2
  SEG(491520, 507904, 24,   64,   256, s6, d6)   // pw0     -> WTP0
  SEG(507904, 524288, 40,   64,   256, s7, d7)   // pw1     -> WTP1
  SEG(524288, 557056, 112,  128,  256, s8, d8)   // pw2     -> WTP2
  SEG(557056, 884736, 1280, 1280, 256, s9, d9)   // pw3     -> WTP3
#undef SEG
}

// ---------- consolidated grd transpose+cast+pad (element-parallel) ----------
__global__ __launch_bounds__(256) void tpad_all_kernel(
    const float* g0, const float* g1, const float* g2, const float* g3,
    __hip_bfloat16* x0, __hip_bfloat16* x1, __hip_bfloat16* x2,
    __hip_bfloat16* x3) {
  const int i = blockIdx.x * 256 + threadIdx.x;
#define TSEG(lo, hi, C, Kp, HW, src, dst)                                      \
  if (i < (hi)) {                                                              \
    const int j = i - (lo);                                                    \
    const int row = j / (Kp);                                                  \
    const int k = j - row * (Kp);                                              \
    const int b = row / (HW);                                                  \
    const int hw = row - b * (HW);                                             \
    dst[j] = (k < (C))                                                         \
        ? __float2bfloat16(src[((size_t)b * (C) + k) * (HW) + hw])             \
        : __float2bfloat16(0.f);                                               \
    return;                                                                    \
  }
  TSEG(0,       1048576, 24,   64,   4096, g0, x0)
  TSEG(1048576, 1310720, 40,   64,   1024, g1, x1)
  TSEG(1310720, 1441792, 112,  128,  256,  g2, x2)
  TSEG(1441792, 1769472, 1280, 1280, 64,   g3, x3)
#undef TSEG
}

// ---------------- GroupNorm (32 groups of 8 ch) -> bf16, level-major --------
__global__ __launch_bounds__(256) void gn_kernel(
    const float* __restrict__ val, __hip_bfloat16* __restrict__ valb,
    const float* __restrict__ gg0, const float* __restrict__ gb0,
    const float* __restrict__ gg1, const float* __restrict__ gb1,
    const float* __restrict__ gg2, const float* __restrict__ gb2,
    const float* __restrict__ gg3, const float* __restrict__ gb3) {
  const int bid = blockIdx.x;            // b*128 + l*32 + grp
  const int grp = bid & 31;
  const int l = (bid >> 5) & 3;
  const int b = bid >> 7;
  int HW, startB; const float *gg, *gbeta;
  if (l == 0)      { HW = 4096; startB = 0;     gg = gg0; gbeta = gb0; }
  else if (l == 1) { HW = 1024; startB = 16384; gg = gg1; gbeta = gb1; }
  else if (l == 2) { HW = 256;  startB = 20480; gg = gg2; gbeta = gb2; }
  else             { HW = 64;   startB = 21504; gg = gg3; gbeta = gb3; }
  const int n = HW * 8;
  const size_t base = ((size_t)(startB + b * HW)) * 256 + grp * 8;
  float s = 0.f, s2 = 0.f;
  for (int i = threadIdx.x; i < n; i += 256) {
    float x = val[base + (size_t)(i >> 3) * 256 + (i & 7)];
    s += x; s2 += x * x;
  }
  s = wred(s); s2 = wred(s2);
  __shared__ float red[8];
  const int wv = threadIdx.x >> 6;
  if ((threadIdx.x & 63) == 0) { red[wv] = s; red[4 + wv] = s2; }
  __syncthreads();
  const float S = red[0] + red[1] + red[2] + red[3];
  const float S2 = red[4] + red[5] + red[6] + red[7];
  const float inv_n = 1.f / (float)n;
  const float mu = S * inv_n;
  const float var = S2 * inv_n - mu * mu;
  const float rstd = rsqrtf(var + 1e-5f);
  for (int i = threadIdx.x; i < n; i += 256) {
    const int j = i & 7;
    const int e = grp * 8 + j;
    const size_t idx = base + (size_t)(i >> 3) * 256 + j;
    const float y = (val[idx] - mu) * rstd * gg[e] + gbeta[e];
    valb[idx] = __float2bfloat16(y);
  }
}

// ---------------- bf16 MFMA GEMM: C[M][N] = X[M][K] * Wt[N][K]^T + bias ------
// 128x128 tile, BK=64, 4 waves (2x2), 4x4 16x16x32 frags per wave.
// !XF32: As/Bs staged via global_load_lds (16B/lane, linear LDS).
// XF32: X fp32, converted to bf16 during reg staging.
// MODE 0: Cf=f32(acc+bias)  1: Cb=bf16(relu)  2: +2Q dual-write  3: Cb=bf16
template <int MODE, bool XF32>
__global__ __launch_bounds__(256) void gemm_bt(
    const void* __restrict__ Xv, const __hip_bfloat16* __restrict__ Wt,
    const float* __restrict__ bias, float* __restrict__ Cf,
    __hip_bfloat16* __restrict__ Cb, const float* __restrict__ Qres,
    int M, int N, int K) {
  const int m0 = blockIdx.x * 128;
  const int n0 = blockIdx.y * 128;
  const int tid = threadIdx.x;
  const int wave = tid >> 6;
  const int lane = tid & 63;
  const int wm = wave >> 1;
  const int wn = wave & 1;
  const int l15 = lane & 15;
  const int l4 = lane >> 4;
  __shared__ __align__(16) __hip_bfloat16 As[128 * 64];
  __shared__ __align__(16) __hip_bfloat16 Bs[128 * 64];
  f32x4 acc[4][4];
#pragma unroll
  for (int m = 0; m < 4; ++m)
#pragma unroll
    for (int n = 0; n < 4; ++n) acc[m][n] = (f32x4){0.f, 0.f, 0.f, 0.f};

  for (int k0 = 0; k0 < K; k0 += 64) {
#pragma unroll
    for (int j = 0; j < 4; ++j) {
      const int e = (j * 256 + tid) * 8;
      const int r = e >> 6;
      const int k = e & 63;
      if constexpr (XF32) {
        const float* Xf = (const float*)Xv;
        const float4 a = *reinterpret_cast<const float4*>(&Xf[(size_t)(m0 + r) * K + k0 + k]);
        const float4 b = *reinterpret_cast<const float4*>(&Xf[(size_t)(m0 + r) * K + k0 + k + 4]);
        union { __hip_bfloat16 h[8]; short8 v; } u;
        u.h[0] = __float2bfloat16(a.x); u.h[1] = __float2bfloat16(a.y);
        u.h[2] = __float2bfloat16(a.z); u.h[3] = __float2bfloat16(a.w);
        u.h[4] = __float2bfloat16(b.x); u.h[5] = __float2bfloat16(b.y);
        u.h[6] = __float2bfloat16(b.z); u.h[7] = __float2bfloat16(b.w);
        *reinterpret_cast<short8*>(&As[e]) = u.v;
        *reinterpret_cast<short8*>(&Bs[e]) =
            *reinterpret_cast<const short8*>(&Wt[(size_t)(n0 + r) * K + k0 + k]);
      } else {
        const __hip_bfloat16* Xb = (const __hip_bfloat16*)Xv;
        GLOAD16(&Xb[(size_t)(m0 + r) * K + k0 + k], &As[e]);
        GLOAD16(&Wt[(size_t)(n0 + r) * K + k0 + k], &Bs[e]);
      }
    }
    __syncthreads();
#pragma unroll
    for (int ks = 0; ks < 2; ++ks) {
      short8 a[4], bfr[4];
#pragma unroll
      for (int m = 0; m < 4; ++m)
        a[m] = *reinterpret_cast<const short8*>(
            &As[(wm * 64 + m * 16 + l15) * 64 + ks * 32 + l4 * 8]);
#pragma unroll
      for (int n = 0; n < 4; ++n)
        bfr[n] = *reinterpret_cast<const short8*>(
            &Bs[(wn * 64 + n * 16 + l15) * 64 + ks * 32 + l4 * 8]);
#pragma unroll
      for (int m = 0; m < 4; ++m)
#pragma unroll
        for (int n = 0; n < 4; ++n)
          acc[m][n] = __builtin_amdgcn_mfma_f32_16x16x32_bf16(a[m], bfr[n], acc[m][n], 0, 0, 0);
    }
    __syncthreads();
  }

#pragma unroll
  for (int m = 0; m < 4; ++m) {
    const int row0 = m0 + wm * 64 + m * 16 + l4 * 4;
#pragma unroll
    for (int n = 0; n < 4; ++n) {
      const int col = n0 + wn * 64 + n * 16 + l15;
      const float bv = bias[col];
#pragma unroll
      for (int r = 0; r < 4; ++r) {
        const size_t ci = (size_t)(row0 + r) * N + col;
        float f = acc[m][n][r] + bv;
        if (MODE == 0) {
          Cf[ci] = f;
        } else if (MODE == 1) {
          Cb[ci] = __float2bfloat16(fmaxf(f, 0.f));
        } else if (MODE == 2) {
          f += 2.f * Qres[ci];
          Cf[ci] = f;
          Cb[ci] = __float2bfloat16(f);
        } else {
          Cb[ci] = __float2bfloat16(f);
        }
      }
    }
  }
}

// ---------------- deformable bilinear sampler (2-phase, fused softmax) ------
// block = 4 queries; 256 threads; <=64 VGPR enforced (8 waves/SIMD — the
// occupancy cliff at VGPR=64 halved waves in r8).
// VB is bf16, level-major. LDS entries XOR-swizzled (tap^h).
__global__ __launch_bounds__(256, 8) void sampler_kernel(
    const __hip_bfloat16* __restrict__ VB, const float* __restrict__ OFFS,
    const float* __restrict__ AWr, __hip_bfloat16* __restrict__ ATT) {
  __shared__ int   sIdx[512 * 4];
  __shared__ float sW[512 * 4];
  const int blk = blockIdx.x;              // [0, B*NQ/4)
  const int b = blk >> 12;                 // NQ/4 = 4096 blocks per batch
  const int q0 = (blk & 4095) << 2;        // within-batch first query
  const int bid0 = blk << 2;               // global row (b*NQ + q0)

  // ---- phase 1: geometry + softmax ----
  for (int j = threadIdx.x; j < 512; j += 256) {
    const int q   = j >> 7;                // 0..3
    const int h   = (j >> 4) & 7;
    const int tap = j & 15;                // l*4 + p
    const int l = tap >> 2;
    const int gq = bid0 + q;
    const int qq = q0 + q;
    const float rx = (float)(qq & 127) * (1.f / 127.f);
    const float ry = (float)(qq >> 7) * (1.f / 127.f);
    const float2 oxy = *reinterpret_cast<const float2*>(
        &OFFS[(size_t)gq * 256 + h * 32 + tap * 2]);
    const float s_raw = AWr[(size_t)gq * 128 + h * 16 + tap];
    // softmax over 16-lane tap group (lanes j..j^15 share (q,h))
    float mx = s_raw;
#pragma unroll
    for (int o = 1; o < 16; o <<= 1) mx = fmaxf(mx, __shfl_xor(mx, o));
    const float ex = __expf(s_raw - mx);
    float sum = ex;
#pragma unroll
    for (int o = 1; o < 16; o <<= 1) sum += __shfl_xor(sum, o);
    const float aw = ex / sum;

    const int W = 64 >> l;
    const int HWl = W * W;
    const int startB = (l == 0) ? 0 : (l == 1) ? 16384 : (l == 2) ? 20480 : 21504;
    const int rowbase = startB + b * HWl;
    const float fW = (float)W;
    const float x = rx * fW + oxy.x - 0.5f;
    const float y = ry * fW + oxy.y - 0.5f;
    const float x0f = floorf(x);
    const float y0f = floorf(y);
    const int x0 = (int)x0f;
    const int y0 = (int)y0f;
    const float dx = x - x0f;
    const float dy = y - y0f;
    const int x1 = x0 + 1, y1 = y0 + 1;
    const float mx0 = (x0 >= 0 && x0 < W) ? 1.f : 0.f;
    const float mx1 = (x1 >= 0 && x1 < W) ? 1.f : 0.f;
    const float my0 = (y0 >= 0 && y0 < W) ? 1.f : 0.f;
    const float my1 = (y1 >= 0 && y1 < W) ? 1.f : 0.f;
    const int x0c = min(max(x0, 0), W - 1);
    const int x1c = min(max(x1, 0), W - 1);
    const int y0c = min(max(y0, 0), W - 1);
    const int y1c = min(max(y1, 0), W - 1);
    int4 I;
    I.x = rowbase + y0c * W + x0c;
    I.y = rowbase + y0c * W + x1c;
    I.z = rowbase + y1c * W + x0c;
    I.w = rowbase + y1c * W + x1c;
    float4 Wv;
    Wv.x = aw * (1.f - dx) * (1.f - dy) * (mx0 * my0);
    Wv.y = aw * dx * (1.f - dy) * (mx1 * my0);
    Wv.z = aw * (1.f - dx) * dy * (mx0 * my1);
    Wv.w = aw * dx * dy * (mx1 * my1);
    const int pj = (j & ~15) | (tap ^ h);  // XOR-swizzle
    *reinterpret_cast<int4*>(&sIdx[pj * 4]) = I;
    *reinterpret_cast<float4*>(&sW[pj * 4]) = Wv;
  }
  __syncthreads();

  // ---- phase 2: bf16 gather (8B/lane), scalar accumulators ----
  const int q  = threadIdx.x >> 6;         // 0..3
  const int h  = (threadIdx.x >> 3) & 7;   // 0..7
  const int dq = threadIdx.x & 7;          // 0..7 (covers 4 dims each)
  const u32* vb = (const u32*)((const unsigned short*)VB + h * 32 + dq * 4);
  const int jbase = (q * 8 + h) * 16;
  float a0 = 0.f, a1 = 0.f, a2 = 0.f, a3 = 0.f;
#pragma unroll 4
  for (int tap = 0; tap < 16; ++tap) {
    const int pj = jbase + (tap ^ h);      // same swizzle as the write
    const int4   I  = *reinterpret_cast<const int4*>(&sIdx[pj * 4]);
    const float4 Wv = *reinterpret_cast<const float4*>(&sW[pj * 4]);
    const uint2 r00 = *reinterpret_cast<const uint2*>(vb + ((size_t)I.x << 7));
    const uint2 r01 = *reinterpret_cast<const uint2*>(vb + ((size_t)I.y << 7));
    const uint2 r10 = *reinterpret_cast<const uint2*>(vb + ((size_t)I.z << 7));
    const uint2 r11 = *reinterpret_cast<const uint2*>(vb + ((size_t)I.w << 7));
    a0 += blo(r00.x) * Wv.x + blo(r01.x) * Wv.y + blo(r10.x) * Wv.z + blo(r11.x) * Wv.w;
    a1 += bhi(r00.x) * Wv.x + bhi(r01.x) * Wv.y + bhi(r10.x) * Wv.z + bhi(r11.x) * Wv.w;
    a2 += blo(r00.y) * Wv.x + blo(r01.y) * Wv.y + blo(r10.y) * Wv.z + blo(r11.y) * Wv.w;
    a3 += bhi(r00.y) * Wv.x + bhi(r01.y) * Wv.y + bhi(r10.y) * Wv.z + bhi(r11.y) * Wv.w;
  }
  union { __hip_bfloat16 hh[4]; short4v v; } u;
  u.hh[0] = __float2bfloat16(a0);
  u.hh[1] = __float2bfloat16(a1);
  u.hh[2] = __float2bfloat16(a2);
  u.hh[3] = __float2bfloat16(a3);
  *reinterpret_cast<short4v*>(
      &ATT[(size_t)(bid0 + q) * 256 + h * 32 + dq * 4]) = u.v;
}

// ---------------- LayerNorm(T bf16) + add into out (out holds fused) --------
__global__ __launch_bounds__(256) void ln_add_kernel(
    const __hip_bfloat16* __restrict__ T, const float* __restrict__ lng,
    const float* __restrict__ lnb, float* __restrict__ out) {
  const size_t row = blockIdx.x;
  const int e = threadIdx.x;
  const float t = __bfloat162float(T[row * 256 + e]);
  float s = wred(t);
  float s2 = wred(t * t);
  __shared__ float red[8];
  const int wv = e >> 6;
  if ((e & 63) == 0) { red[wv] = s; red[4 + wv] = s2; }
  __syncthreads();
  const float S = red[0] + red[1] + red[2] + red[3];
  const float S2 = red[4] + red[5] + red[6] + red[7];
  const float mu = S * (1.f / 256.f);
  const float var = S2 * (1.f / 256.f) - mu * mu;
  const float y = (t - mu) * rsqrtf(var + 1e-5f) * lng[e] + lnb[e];
  out[row * 256 + e] += y;
}

extern "C" void kernel_launch(void* const* d_in, const int* in_sizes, int n_in,
                              void* d_out, int out_size, void* d_ws, size_t ws_size,
                              hipStream_t stream) {
  const float* Q  = (const float*)d_in[0];
  const float* g0 = (const float*)d_in[1];
  const float* g1 = (const float*)d_in[2];
  const float* g2 = (const float*)d_in[3];
  const float* g3 = (const float*)d_in[4];
  // d_in[5] = batch_size (fixed 4)
  const float* pw0 = (const float*)d_in[6];
  const float* pb0 = (const float*)d_in[7];
  const float* gg0 = (const float*)d_in[8];
  const float* gb0 = (const float*)d_in[9];
  const float* pw1 = (const float*)d_in[10];
  const float* pb1 = (const float*)d_in[11];
  const float* gg1 = (const float*)d_in[12];
  const float* gb1 = (const float*)d_in[13];
  const float* pw2 = (const float*)d_in[14];
  const float* pb2 = (const float*)d_in[15];
  const float* gg2 = (const float*)d_in[16];
  const float* gb2 = (const float*)d_in[17];
  const float* pw3 = (const float*)d_in[18];
  const float* pb3 = (const float*)d_in[19];
  const float* gg3 = (const float*)d_in[20];
  const float* gb3 = (const float*)d_in[21];
  const float* value_w = (const float*)d_in[22];
  const float* value_b = (const float*)d_in[23];
  const float* off_w   = (const float*)d_in[24];
  const float* off_b   = (const float*)d_in[25];
  const float* attw_w  = (const float*)d_in[26];
  const float* attw_b  = (const float*)d_in[27];
  const float* out_w   = (const float*)d_in[28];
  const float* out_b   = (const float*)d_in[29];
  const float* lin1_w  = (const float*)d_in[30];
  const float* lin1_b  = (const float*)d_in[31];
  const float* lin2_w  = (const float*)d_in[32];
  const float* lin2_b  = (const float*)d_in[33];
  const float* ln_g    = (const float*)d_in[34];
  const float* ln_b    = (const float*)d_in[35];

  char* ws = (char*)d_ws;
  __hip_bfloat16* WT_VALUE = (__hip_bfloat16*)(ws + 0);        // 131072
  __hip_bfloat16* WT_OFF   = (__hip_bfloat16*)(ws + 131072);   // 131072
  __hip_bfloat16* WT_ATTW  = (__hip_bfloat16*)(ws + 262144);   // 65536
  __hip_bfloat16* WT_OUT   = (__hip_bfloat16*)(ws + 327680);   // 131072
  __hip_bfloat16* WT_LIN1  = (__hip_bfloat16*)(ws + 458752);   // 262144
  __hip_bfloat16* WT_LIN2  = (__hip_bfloat16*)(ws + 720896);   // 262144 -> 983040
  __hip_bfloat16* WTP0     = (__hip_bfloat16*)(ws + 983040);   // 32768
  __hip_bfloat16* WTP1     = (__hip_bfloat16*)(ws + 1015808);  // 32768
  __hip_bfloat16* WTP2     = (__hip_bfloat16*)(ws + 1048576);  // 65536
  __hip_bfloat16* WTP3     = (__hip_bfloat16*)(ws + 1114112);  // 655360 -> 1769472
  __hip_bfloat16* XP0      = (__hip_bfloat16*)(ws + 1769472);  // -> 3866624
  __hip_bfloat16* XP1      = (__hip_bfloat16*)(ws + 3866624);  // -> 4390912
  __hip_bfloat16* XP2      = (__hip_bfloat16*)(ws + 4390912);  // -> 4653056
  __hip_bfloat16* XP3      = (__hip_bfloat16*)(ws + 4653056);  // -> 5308416
  float*          VAL      = (float*)(ws + 34406400);          // -> 56688640
  __hip_bfloat16* VALB     = (__hip_bfloat16*)(ws + 23265280); // -> 34406400
  __hip_bfloat16* VB       = (__hip_bfloat16*)(ws + 983040);   // bf16 value -> 12124160
  float*          AWr      = (float*)(ws + 23265280);          // raw scores -> 56819712
  __hip_bfloat16* ATT      = (__hip_bfloat16*)(ws + 56819712); // -> 90374144 (peak)
  __hip_bfloat16* FUSEDB   = (__hip_bfloat16*)(ws + 983040);   // -> 34537472
  __hip_bfloat16* HIDH     = (__hip_bfloat16*)(ws + 34537472); // -> 68091904
  __hip_bfloat16* T16H     = (__hip_bfloat16*)(ws + 68091904); // -> 84869120
  float*          OFFS     = (float*)d_out;                    // 64MB, dead before FUSED
  float*          FUSED    = (float*)d_out;                    // fused residual -> output

  // 1. all weight prep in one launch
  prep_kernel<<<3456, 256, 0, stream>>>(value_w, off_w, attw_w, out_w, lin1_w,
                                        lin2_w, pw0, pw1, pw2, pw3,
                                        WT_VALUE, WT_OFF, WT_ATTW, WT_OUT,
                                        WT_LIN1, WT_LIN2, WTP0, WTP1, WTP2, WTP3);

  // 2. grd transpose/pad in one launch
  tpad_all_kernel<<<6912, 256, 0, stream>>>(g0, g1, g2, g3, XP0, XP1, XP2, XP3);

  // 3. proj GEMMs -> VAL (level-major) ; GN -> VALB ; value GEMM -> VB (bf16)
  gemm_bt<0, false><<<dim3(128, 2), 256, 0, stream>>>(XP0, WTP0, pb0, VAL,
                                                      nullptr, nullptr, 16384, 256, 64);
  gemm_bt<0, false><<<dim3(32, 2), 256, 0, stream>>>(XP1, WTP1, pb1, VAL + (size_t)16384 * 256,
                                                     nullptr, nullptr, 4096, 256, 64);
  gemm_bt<0, false><<<dim3(8, 2), 256, 0, stream>>>(XP2, WTP2, pb2, VAL + (size_t)20480 * 256,
                                                    nullptr, nullptr, 1024, 256, 128);
  gemm_bt<0, false><<<dim3(2, 2), 256, 0, stream>>>(XP3, WTP3, pb3, VAL + (size_t)21504 * 256,
                                                    nullptr, nullptr, 256, 256, 1280);
  gn_kernel<<<512, 256, 0, stream>>>(VAL, VALB, gg0, gb0, gg1, gb1, gg2, gb2, gg3, gb3);
  gemm_bt<3, false><<<dim3(170, 2), 256, 0, stream>>>(VALB, WT_VALUE, value_b, nullptr,
                                                      VB, nullptr, 21760, 256, 256);

  // 4. query branch: offsets (-> d_out) + raw attention scores; X = Q fp32
  gemm_bt<0, true><<<dim3(512, 2), 256, 0, stream>>>(Q, WT_OFF, off_b, OFFS,
                                                     nullptr, nullptr, 65536, 256, 256);
  gemm_bt<0, true><<<dim3(512, 1), 256, 0, stream>>>(Q, WT_ATTW, attw_b, AWr,
                                                     nullptr, nullptr, 65536, 128, 256);

  // 5. deformable sampling (softmax fused) -> ATT (bf16)
  sampler_kernel<<<16384, 256, 0, stream>>>(VB, OFFS, AWr, ATT);

  // 6. out proj + 2Q residual: FUSED(f32, d_out; kills OFFS) + FUSEDB(bf16)
  gemm_bt<2, false><<<dim3(512, 2), 256, 0, stream>>>(ATT, WT_OUT, out_b, FUSED,
                                                      FUSEDB, Q, 65536, 256, 256);

  // 7. FFN in two M-halves of 32768 rows:
  //    lin1(relu)->HIDH, lin2->T16H bf16, LN+add into FUSED.
  for (int h = 0; h < 2; ++h) {
    const __hip_bfloat16* Xh = FUSEDB + (size_t)h * 32768 * 256;
    gemm_bt<1, false><<<dim3(256, 4), 256, 0, stream>>>(Xh, WT_LIN1, lin1_b, nullptr,
                                                        HIDH, nullptr, 32768, 512, 256);
    gemm_bt<3, false><<<dim3(256, 2), 256, 0, stream>>>(HIDH, WT_LIN2, lin2_b, nullptr,
                                                        T16H, nullptr, 32768, 256, 512);
    ln_add_kernel<<<32768, 256, 0, stream>>>(T16H, ln_g, ln_b,
                                             FUSED + (size_t)h * 32768 * 256);
  }
}